// Round 1
// baseline (626.254 us; speedup 1.0000x reference)
//
#include <hip/hip_runtime.h>

#define N_NODES 50000
#define N_EDGES 800000
#define IN_CH 128
#define HID 64
#define OUT_CH 32

// ---------------- init: deg = 1 (self-loop), zero aggregation buffer B ----
__global__ __launch_bounds__(256) void k_init(float* deg, float* aggB) {
    int i = blockIdx.x * 256 + threadIdx.x;         // grid covers N_NODES*HID
    if (i < N_NODES) deg[i] = 1.0f;
    if (i < N_NODES * HID) aggB[i] = 0.0f;
}

__global__ __launch_bounds__(256) void k_zero(float* p, int n) {
    int i = blockIdx.x * 256 + threadIdx.x;
    if (i < n) p[i] = 0.0f;
}

// ---------------- degree count over dst ----------------------------------
__global__ __launch_bounds__(256) void k_deg(const int* ei, float* deg) {
    int e = blockIdx.x * 256 + threadIdx.x;
    if (e < N_EDGES) atomicAdd(&deg[ei[N_EDGES + e]], 1.0f);
}

__global__ __launch_bounds__(256) void k_rsqrt(float* deg) {
    int i = blockIdx.x * 256 + threadIdx.x;
    if (i < N_NODES) deg[i] = rsqrtf(deg[i]);       // deg >= 1 always
}

// ---------------- t1 = x @ W1  (50000x128 @ 128x64) -----------------------
// block = 256 = 4 nodes x 64 channels; x rows staged in LDS (broadcast reads)
__global__ __launch_bounds__(256) void k_mm1(const float* __restrict__ x,
                                             const float* __restrict__ W1,
                                             float* __restrict__ t1) {
    __shared__ float xs[4 * IN_CH];
    int n0 = blockIdx.x * 4;
    int tid = threadIdx.x;
    xs[tid]       = x[n0 * IN_CH + tid];
    xs[tid + 256] = x[n0 * IN_CH + tid + 256];
    __syncthreads();
    int node = tid >> 6, c = tid & 63;
    const float* xr = xs + node * IN_CH;
    float acc = 0.0f;
#pragma unroll 8
    for (int k = 0; k < IN_CH; ++k) acc += xr[k] * W1[k * HID + c];
    t1[(n0 + node) * HID + c] = acc;                // 50000 % 4 == 0, no tail
}

// ---------------- aggregation: one wave per edge item ---------------------
// items [0,E) are edges, [E, E+N) are self-loops (src=dst=i, norm=dis^2).
// layer2 fuses h = relu(agg1 + b1) into the gather.
__global__ __launch_bounds__(256) void k_agg(const int* __restrict__ ei,
                                             const float* __restrict__ dis,
                                             const float* __restrict__ in,
                                             const float* __restrict__ bias,
                                             float* __restrict__ out,
                                             int apply_relu) {
    int w = (blockIdx.x * 256 + threadIdx.x) >> 6;  // global wave id
    int lane = threadIdx.x & 63;
    if (w >= N_EDGES + N_NODES) return;
    int s, d; float nrm;
    if (w < N_EDGES) {
        s = ei[w]; d = ei[N_EDGES + w];
        nrm = dis[s] * dis[d];
    } else {
        s = d = w - N_EDGES;
        float r = dis[s]; nrm = r * r;
    }
    float v = in[s * HID + lane];
    if (apply_relu) v = fmaxf(v + bias[lane], 0.0f);
    atomicAdd(&out[d * HID + lane], v * nrm);
}

// ---------------- out = agg2 @ [W_mu | W_logstd] + bias -------------------
// block = 256 = 4 nodes x 64 out-channels (c<32 -> mu, c>=32 -> logstd)
__global__ __launch_bounds__(256) void k_mm2(const float* __restrict__ agg2,
                                             const float* __restrict__ Wmu,
                                             const float* __restrict__ bmu,
                                             const float* __restrict__ Wls,
                                             const float* __restrict__ bls,
                                             float* __restrict__ out) {
    __shared__ float hs[4 * HID];
    int n0 = blockIdx.x * 4;
    int tid = threadIdx.x;
    hs[tid] = agg2[n0 * HID + tid];
    __syncthreads();
    int node = tid >> 6, c = tid & 63;
    const float* hr = hs + node * HID;
    int cc = c & 31;
    const float* W = (c < 32) ? Wmu : Wls;
    float acc = (c < 32) ? bmu[cc] : bls[cc];
#pragma unroll 8
    for (int k = 0; k < HID; ++k) acc += hr[k] * W[k * OUT_CH + cc];
    int n = n0 + node;
    if (c < 32) out[n * OUT_CH + c] = acc;
    else        out[N_NODES * OUT_CH + n * OUT_CH + cc] = acc;
}

extern "C" void kernel_launch(void* const* d_in, const int* in_sizes, int n_in,
                              void* d_out, int out_size, void* d_ws, size_t ws_size,
                              hipStream_t stream) {
    const float* x   = (const float*)d_in[0];
    const int*   ei  = (const int*)  d_in[1];
    const float* W1  = (const float*)d_in[2];
    const float* b1  = (const float*)d_in[3];
    const float* Wmu = (const float*)d_in[4];
    const float* bmu = (const float*)d_in[5];
    const float* Wls = (const float*)d_in[6];
    const float* bls = (const float*)d_in[7];
    float* out = (float*)d_out;

    float* ws   = (float*)d_ws;
    float* deg  = ws;                       // N floats (becomes dis in-place)
    float* bufA = ws + 50048;               // N*HID: t1, later reused as agg2
    float* bufB = bufA + N_NODES * HID;     // N*HID: agg1
    // total ws use: 50048 + 2*3.2M floats = ~25.8 MB

    const int NH = N_NODES * HID;           // 3,200,000
    const int agg_blocks = (N_EDGES + N_NODES + 3) / 4;  // 4 waves/block

    k_init <<<(NH + 255) / 256, 256, 0, stream>>>(deg, bufB);
    k_deg  <<<(N_EDGES + 255) / 256, 256, 0, stream>>>(ei, deg);
    k_rsqrt<<<(N_NODES + 255) / 256, 256, 0, stream>>>(deg);
    k_mm1  <<<N_NODES / 4, 256, 0, stream>>>(x, W1, bufA);              // t1
    k_agg  <<<agg_blocks, 256, 0, stream>>>(ei, deg, bufA, nullptr, bufB, 0); // agg1
    k_zero <<<(NH + 255) / 256, 256, 0, stream>>>(bufA, NH);            // agg2 := 0
    k_agg  <<<agg_blocks, 256, 0, stream>>>(ei, deg, bufB, b1, bufA, 1);      // agg2
    k_mm2  <<<N_NODES / 4, 256, 0, stream>>>(bufA, Wmu, bmu, Wls, bls, out);
}

// Round 2
// 412.076 us; speedup vs baseline: 1.5198x; 1.5198x over previous
//
#include <hip/hip_runtime.h>

#define N_NODES 50000
#define N_EDGES 800000
#define IN_CH 128
#define HID 64
#define OUT_CH 32
#define NBLK 196                 // ceil(50000/256) blocks for node-sized kernels

// ---------------- zero int counters ---------------------------------------
__global__ __launch_bounds__(256) void k_zero_i(int* p) {
    p[blockIdx.x * 256 + threadIdx.x] = 0;          // covers 50176 (padded)
}

// ---------------- histogram of dst ----------------------------------------
__global__ __launch_bounds__(256) void k_hist(const int* __restrict__ ei, int* cnt) {
    int e = blockIdx.x * 256 + threadIdx.x;
    if (e < N_EDGES) atomicAdd(&cnt[ei[N_EDGES + e]], 1);
}

// ---------------- dis = rsqrt(deg), deg = cnt + 1 (self-loop) --------------
__global__ __launch_bounds__(256) void k_dis(const int* __restrict__ cnt, float* dis) {
    int i = blockIdx.x * 256 + threadIdx.x;
    if (i < N_NODES) dis[i] = rsqrtf((float)(cnt[i] + 1));
}

// ---------------- scan stage 1: per-block sums -----------------------------
__global__ __launch_bounds__(256) void k_block_sum(const int* __restrict__ cnt, int* partials) {
    __shared__ int s[256];
    int t = threadIdx.x;
    s[t] = cnt[blockIdx.x * 256 + t];               // padded region is zero
    __syncthreads();
    for (int off = 128; off > 0; off >>= 1) {
        if (t < off) s[t] += s[t + off];
        __syncthreads();
    }
    if (t == 0) partials[blockIdx.x] = s[0];
}

// ---------------- scan stage 2: exclusive scan of partials (1 block) -------
__global__ __launch_bounds__(256) void k_scan_partials(int* partials) {
    __shared__ int s[256];
    int t = threadIdx.x;
    int v = (t < NBLK) ? partials[t] : 0;
    s[t] = v;
    __syncthreads();
    for (int off = 1; off < 256; off <<= 1) {
        int a = (t >= off) ? s[t - off] : 0;
        __syncthreads();
        s[t] += a;
        __syncthreads();
    }
    partials[t] = s[t] - v;                         // exclusive
}

// ---------------- scan stage 3: final row_start + cursor init --------------
__global__ __launch_bounds__(256) void k_scan_final(const int* __restrict__ cnt,
                                                    const int* __restrict__ partials,
                                                    int* row_start, int* cur) {
    __shared__ int s[256];
    int t = threadIdx.x;
    int i = blockIdx.x * 256 + t;
    int v = cnt[i];
    s[t] = v;
    __syncthreads();
    for (int off = 1; off < 256; off <<= 1) {
        int a = (t >= off) ? s[t - off] : 0;
        __syncthreads();
        s[t] += a;
        __syncthreads();
    }
    int base = partials[blockIdx.x];
    int excl = base + s[t] - v;
    if (i < N_NODES) { row_start[i] = excl; cur[i] = excl; }
    if (i == N_NODES - 1) row_start[N_NODES] = excl + v;   // == N_EDGES
}

// ---------------- scatter edges into dst-sorted order ----------------------
__global__ __launch_bounds__(256) void k_scatter(const int* __restrict__ ei,
                                                 const float* __restrict__ dis,
                                                 int* cur, int* __restrict__ srcs,
                                                 float* __restrict__ nrm) {
    int e = blockIdx.x * 256 + threadIdx.x;
    if (e >= N_EDGES) return;
    int s = ei[e], d = ei[N_EDGES + e];
    int pos = atomicAdd(&cur[d], 1);
    srcs[pos] = s;
    nrm[pos] = dis[s] * dis[d];
}

// ---------------- t1 = x @ W1  (50000x128 @ 128x64) ------------------------
__global__ __launch_bounds__(256) void k_mm1(const float* __restrict__ x,
                                             const float* __restrict__ W1,
                                             float* __restrict__ t1) {
    __shared__ float xs[4 * IN_CH];
    int n0 = blockIdx.x * 4;
    int tid = threadIdx.x;
    xs[tid]       = x[n0 * IN_CH + tid];
    xs[tid + 256] = x[n0 * IN_CH + tid + 256];
    __syncthreads();
    int node = tid >> 6, c = tid & 63;
    const float* xr = xs + node * IN_CH;
    float acc = 0.0f;
#pragma unroll 8
    for (int k = 0; k < IN_CH; ++k) acc += xr[k] * W1[k * HID + c];
    t1[(n0 + node) * HID + c] = acc;
}

// ---------------- pull aggregation: one wave per dst node ------------------
// acc = dis[d]^2 * in[d] + sum_j nrm[j] * in[srcs[j]]
// apply_relu: out = relu(acc + bias)  (layer-1 epilogue), else raw acc.
__global__ __launch_bounds__(256) void k_agg_csr(const int* __restrict__ srcs,
                                                 const float* __restrict__ nrm,
                                                 const int* __restrict__ row_start,
                                                 const float* __restrict__ dis,
                                                 const float* __restrict__ in,
                                                 const float* __restrict__ bias,
                                                 float* __restrict__ out,
                                                 int apply_relu) {
    int w = (blockIdx.x * 256 + threadIdx.x) >> 6;
    int lane = threadIdx.x & 63;
    if (w >= N_NODES) return;
    int beg = row_start[w], end = row_start[w + 1];
    float r = dis[w];
    float acc = r * r * in[w * HID + lane];
    for (int j = beg; j < end; ++j) {
        int s = srcs[j];
        float nv = nrm[j];
        acc += nv * in[s * HID + lane];
    }
    if (apply_relu) acc = fmaxf(acc + bias[lane], 0.0f);
    out[w * HID + lane] = acc;
}

// ---------------- out = agg2 @ [W_mu | W_logstd] + bias --------------------
__global__ __launch_bounds__(256) void k_mm2(const float* __restrict__ agg2,
                                             const float* __restrict__ Wmu,
                                             const float* __restrict__ bmu,
                                             const float* __restrict__ Wls,
                                             const float* __restrict__ bls,
                                             float* __restrict__ out) {
    __shared__ float hs[4 * HID];
    int n0 = blockIdx.x * 4;
    int tid = threadIdx.x;
    hs[tid] = agg2[n0 * HID + tid];
    __syncthreads();
    int node = tid >> 6, c = tid & 63;
    const float* hr = hs + node * HID;
    int cc = c & 31;
    const float* W = (c < 32) ? Wmu : Wls;
    float acc = (c < 32) ? bmu[cc] : bls[cc];
#pragma unroll 8
    for (int k = 0; k < HID; ++k) acc += hr[k] * W[k * OUT_CH + cc];
    int n = n0 + node;
    if (c < 32) out[n * OUT_CH + c] = acc;
    else        out[N_NODES * OUT_CH + n * OUT_CH + cc] = acc;
}

extern "C" void kernel_launch(void* const* d_in, const int* in_sizes, int n_in,
                              void* d_out, int out_size, void* d_ws, size_t ws_size,
                              hipStream_t stream) {
    const float* x   = (const float*)d_in[0];
    const int*   ei  = (const int*)  d_in[1];
    const float* W1  = (const float*)d_in[2];
    const float* b1  = (const float*)d_in[3];
    const float* Wmu = (const float*)d_in[4];
    const float* bmu = (const float*)d_in[5];
    const float* Wls = (const float*)d_in[6];
    const float* bls = (const float*)d_in[7];
    float* out = (float*)d_out;

    // workspace layout (4-byte units)
    int*   cnt       = (int*)d_ws;                       // [0, 50176)
    float* dis       = (float*)d_ws + 50176;             // 50000
    int*   row_start = (int*)d_ws + 100176;              // 50001 (pad to 150208)
    int*   cur       = (int*)d_ws + 150208;              // 50000
    int*   partials  = (int*)d_ws + 200208;              // 256 (pad to 200512)
    int*   srcs      = (int*)d_ws + 200512;              // 800000
    float* nrm       = (float*)d_ws + 1000512;           // 800000
    float* bufA      = (float*)d_ws + 1800512;           // 3.2M (t1, then agg2)
    float* bufB      = (float*)d_ws + 5000512;           // 3.2M (h)
    // total ≈ 32.8 MB

    k_zero_i       <<<NBLK, 256, 0, stream>>>(cnt);
    k_hist         <<<3125, 256, 0, stream>>>(ei, cnt);
    k_dis          <<<NBLK, 256, 0, stream>>>(cnt, dis);
    k_block_sum    <<<NBLK, 256, 0, stream>>>(cnt, partials);
    k_scan_partials<<<1,    256, 0, stream>>>(partials);
    k_scan_final   <<<NBLK, 256, 0, stream>>>(cnt, partials, row_start, cur);
    k_scatter      <<<3125, 256, 0, stream>>>(ei, dis, cur, srcs, nrm);
    k_mm1          <<<12500, 256, 0, stream>>>(x, W1, bufA);
    k_agg_csr      <<<12500, 256, 0, stream>>>(srcs, nrm, row_start, dis, bufA, b1, bufB, 1);
    k_agg_csr      <<<12500, 256, 0, stream>>>(srcs, nrm, row_start, dis, bufB, nullptr, bufA, 0);
    k_mm2          <<<12500, 256, 0, stream>>>(bufA, Wmu, bmu, Wls, bls, out);
}

// Round 3
// 311.230 us; speedup vs baseline: 2.0122x; 1.3240x over previous
//
#include <hip/hip_runtime.h>

#define N_NODES 50000
#define N_EDGES 800000
#define IN_CH 128
#define HID 64
#define OUT_CH 32
#define NBLK 196                 // ceil(50000/256) blocks for node-sized kernels

// ---------------- zero counters + pk tail pad ------------------------------
__global__ __launch_bounds__(256) void k_zero_i(int* cnt, int2* pk) {
    int i = blockIdx.x * 256 + threadIdx.x;
    cnt[i] = 0;                                      // covers 50176 (padded)
    if (i < 4) pk[N_EDGES + i] = make_int2(0, 0);    // pad for 4-wide agg reads
}

// ---------------- histogram of dst ----------------------------------------
__global__ __launch_bounds__(256) void k_hist(const int* __restrict__ ei, int* cnt) {
    int e = blockIdx.x * 256 + threadIdx.x;
    if (e < N_EDGES) atomicAdd(&cnt[ei[N_EDGES + e]], 1);
}

// ---------------- scan stage 1: per-block sums -----------------------------
__global__ __launch_bounds__(256) void k_block_sum(const int* __restrict__ cnt, int* partials) {
    __shared__ int s[256];
    int t = threadIdx.x;
    s[t] = cnt[blockIdx.x * 256 + t];
    __syncthreads();
    for (int off = 128; off > 0; off >>= 1) {
        if (t < off) s[t] += s[t + off];
        __syncthreads();
    }
    if (t == 0) partials[blockIdx.x] = s[0];
}

// ---------------- scan stage 2: exclusive scan of partials (1 block) -------
__global__ __launch_bounds__(256) void k_scan_partials(int* partials) {
    __shared__ int s[256];
    int t = threadIdx.x;
    int v = (t < NBLK) ? partials[t] : 0;
    s[t] = v;
    __syncthreads();
    for (int off = 1; off < 256; off <<= 1) {
        int a = (t >= off) ? s[t - off] : 0;
        __syncthreads();
        s[t] += a;
        __syncthreads();
    }
    partials[t] = s[t] - v;                          // exclusive
}

// ---------------- scan stage 3: row_start + cursors + dis ------------------
__global__ __launch_bounds__(256) void k_scan_final(const int* __restrict__ cnt,
                                                    const int* __restrict__ partials,
                                                    int* row_start, int* cur,
                                                    float* dis) {
    __shared__ int s[256];
    int t = threadIdx.x;
    int i = blockIdx.x * 256 + t;
    int v = cnt[i];
    s[t] = v;
    __syncthreads();
    for (int off = 1; off < 256; off <<= 1) {
        int a = (t >= off) ? s[t - off] : 0;
        __syncthreads();
        s[t] += a;
        __syncthreads();
    }
    int base = partials[blockIdx.x];
    int excl = base + s[t] - v;
    if (i < N_NODES) {
        row_start[i] = excl;
        cur[i] = excl;
        dis[i] = rsqrtf((float)(v + 1));             // self-loop included
    }
    if (i == N_NODES - 1) row_start[N_NODES] = excl + v;   // == N_EDGES
}

// ---------------- scatter edges (packed src+norm, one 8B store) ------------
__global__ __launch_bounds__(256) void k_scatter(const int* __restrict__ ei,
                                                 const float* __restrict__ dis,
                                                 int* cur, int2* __restrict__ pk) {
    int e = blockIdx.x * 256 + threadIdx.x;
    if (e >= N_EDGES) return;
    int s = ei[e], d = ei[N_EDGES + e];
    int pos = atomicAdd(&cur[d], 1);
    pk[pos] = make_int2(s, __float_as_int(dis[s] * dis[d]));
}

// ---------------- t1 = x @ W1  (50000x128 @ 128x64) ------------------------
__global__ __launch_bounds__(256) void k_mm1(const float* __restrict__ x,
                                             const float* __restrict__ W1,
                                             float* __restrict__ t1) {
    __shared__ float xs[4 * IN_CH];
    int n0 = blockIdx.x * 4;
    int tid = threadIdx.x;
    xs[tid]       = x[n0 * IN_CH + tid];
    xs[tid + 256] = x[n0 * IN_CH + tid + 256];
    __syncthreads();
    int node = tid >> 6, c = tid & 63;
    const float* xr = xs + node * IN_CH;
    float acc = 0.0f;
#pragma unroll 8
    for (int k = 0; k < IN_CH; ++k) acc += xr[k] * W1[k * HID + c];
    t1[(n0 + node) * HID + c] = acc;
}

// ---------------- pull aggregation, 4 edges/iteration ----------------------
// wave = 4 edge-groups x 16 lanes; lane loads float4 (16B) -> one gather
// instruction covers 4 independent edges (1KB in flight).
__global__ __launch_bounds__(256) void k_agg4(const int2* __restrict__ pk,
                                              const int* __restrict__ row_start,
                                              const float* __restrict__ dis,
                                              const float* __restrict__ in,
                                              const float* __restrict__ bias,
                                              float* __restrict__ out,
                                              int apply_relu) {
    int w = (blockIdx.x * 256 + threadIdx.x) >> 6;
    if (w >= N_NODES) return;
    int lane = threadIdx.x & 63;
    int egrp = lane >> 4, csub = lane & 15;
    int beg = row_start[w], end = row_start[w + 1];
    const float4* __restrict__ in4 = (const float4*)in;
    float4 acc = make_float4(0.f, 0.f, 0.f, 0.f);
#pragma unroll 2
    for (int base = beg; base < end; base += 4) {
        int je = base + egrp;                        // pk padded by 4 entries
        int2 p = pk[je];
        float nv = (je < end) ? __int_as_float(p.y) : 0.0f;
        float4 v = in4[p.x * 16 + csub];
        acc.x += nv * v.x; acc.y += nv * v.y;
        acc.z += nv * v.z; acc.w += nv * v.w;
    }
    // reduce across the 4 edge groups (lane bits 4,5)
    for (int m = 16; m <= 32; m <<= 1) {
        acc.x += __shfl_xor(acc.x, m, 64);
        acc.y += __shfl_xor(acc.y, m, 64);
        acc.z += __shfl_xor(acc.z, m, 64);
        acc.w += __shfl_xor(acc.w, m, 64);
    }
    if (egrp == 0) {
        float r = dis[w]; float rr = r * r;
        float4 sv = in4[w * 16 + csub];              // self-loop
        acc.x += rr * sv.x; acc.y += rr * sv.y;
        acc.z += rr * sv.z; acc.w += rr * sv.w;
        if (apply_relu) {
            float4 b = ((const float4*)bias)[csub];
            acc.x = fmaxf(acc.x + b.x, 0.f);
            acc.y = fmaxf(acc.y + b.y, 0.f);
            acc.z = fmaxf(acc.z + b.z, 0.f);
            acc.w = fmaxf(acc.w + b.w, 0.f);
        }
        ((float4*)out)[w * 16 + csub] = acc;
    }
}

// ---------------- out = agg2 @ [W_mu | W_logstd] + bias --------------------
__global__ __launch_bounds__(256) void k_mm2(const float* __restrict__ agg2,
                                             const float* __restrict__ Wmu,
                                             const float* __restrict__ bmu,
                                             const float* __restrict__ Wls,
                                             const float* __restrict__ bls,
                                             float* __restrict__ out) {
    __shared__ float hs[4 * HID];
    int n0 = blockIdx.x * 4;
    int tid = threadIdx.x;
    hs[tid] = agg2[n0 * HID + tid];
    __syncthreads();
    int node = tid >> 6, c = tid & 63;
    const float* hr = hs + node * HID;
    int cc = c & 31;
    const float* W = (c < 32) ? Wmu : Wls;
    float acc = (c < 32) ? bmu[cc] : bls[cc];
#pragma unroll 8
    for (int k = 0; k < HID; ++k) acc += hr[k] * W[k * OUT_CH + cc];
    int n = n0 + node;
    if (c < 32) out[n * OUT_CH + c] = acc;
    else        out[N_NODES * OUT_CH + n * OUT_CH + cc] = acc;
}

extern "C" void kernel_launch(void* const* d_in, const int* in_sizes, int n_in,
                              void* d_out, int out_size, void* d_ws, size_t ws_size,
                              hipStream_t stream) {
    const float* x   = (const float*)d_in[0];
    const int*   ei  = (const int*)  d_in[1];
    const float* W1  = (const float*)d_in[2];
    const float* b1  = (const float*)d_in[3];
    const float* Wmu = (const float*)d_in[4];
    const float* bmu = (const float*)d_in[5];
    const float* Wls = (const float*)d_in[6];
    const float* bls = (const float*)d_in[7];
    float* out = (float*)d_out;

    // workspace layout (4-byte units)
    int*   cnt       = (int*)d_ws;                       // [0, 50176)
    float* dis       = (float*)d_ws + 50176;             // 50000
    int*   row_start = (int*)d_ws + 100176;              // 50001 -> pad 150208
    int*   cur       = (int*)d_ws + 150208;              // 50000
    int*   partials  = (int*)d_ws + 200208;              // 256 -> pad 200512
    int2*  pk        = (int2*)((int*)d_ws + 200512);     // 800004 pairs (8B aligned)
    float* bufA      = (float*)d_ws + 1800576;           // 3.2M (t1, then agg2)
    float* bufB      = (float*)d_ws + 5000576;           // 3.2M (h)
    // total ≈ 32.8 MB

    k_zero_i       <<<NBLK, 256, 0, stream>>>(cnt, pk);
    k_hist         <<<3125, 256, 0, stream>>>(ei, cnt);
    k_block_sum    <<<NBLK, 256, 0, stream>>>(cnt, partials);
    k_scan_partials<<<1,    256, 0, stream>>>(partials);
    k_scan_final   <<<NBLK, 256, 0, stream>>>(cnt, partials, row_start, cur, dis);
    k_scatter      <<<3125, 256, 0, stream>>>(ei, dis, cur, pk);
    k_mm1          <<<12500, 256, 0, stream>>>(x, W1, bufA);
    k_agg4         <<<12500, 256, 0, stream>>>(pk, row_start, dis, bufA, b1, bufB, 1);
    k_agg4         <<<12500, 256, 0, stream>>>(pk, row_start, dis, bufB, nullptr, bufA, 0);
    k_mm2          <<<12500, 256, 0, stream>>>(bufA, Wmu, bmu, Wls, bls, out);
}

// Round 4
// 260.841 us; speedup vs baseline: 2.4009x; 1.1932x over previous
//
#include <hip/hip_runtime.h>

#define N_NODES 50000
#define N_EDGES 800000
#define IN_CH 128
#define HID 64
#define OUT_CH 32
#define NBLK 196                 // ceil(50000/256) blocks for node-sized kernels

// ---------------- zero counters + pk tail pad ------------------------------
__global__ __launch_bounds__(256) void k_zero_i(int* cnt, int2* pk) {
    int i = blockIdx.x * 256 + threadIdx.x;
    cnt[i] = 0;                                      // covers 50176 (padded)
    if (i < 16) pk[N_EDGES + i] = make_int2(0, 0);   // pad for unroll-4 agg reads
}

// ---------------- histogram of dst ----------------------------------------
__global__ __launch_bounds__(256) void k_hist(const int* __restrict__ ei, int* cnt) {
    int e = blockIdx.x * 256 + threadIdx.x;
    if (e < N_EDGES) atomicAdd(&cnt[ei[N_EDGES + e]], 1);
}

// ---------------- scan stage 1: per-block sums -----------------------------
__global__ __launch_bounds__(256) void k_block_sum(const int* __restrict__ cnt, int* partials) {
    __shared__ int s[256];
    int t = threadIdx.x;
    s[t] = cnt[blockIdx.x * 256 + t];
    __syncthreads();
    for (int off = 128; off > 0; off >>= 1) {
        if (t < off) s[t] += s[t + off];
        __syncthreads();
    }
    if (t == 0) partials[blockIdx.x] = s[0];
}

// ---------------- scan stage 2: exclusive scan of partials (1 block) -------
__global__ __launch_bounds__(256) void k_scan_partials(int* partials) {
    __shared__ int s[256];
    int t = threadIdx.x;
    int v = (t < NBLK) ? partials[t] : 0;
    s[t] = v;
    __syncthreads();
    for (int off = 1; off < 256; off <<= 1) {
        int a = (t >= off) ? s[t - off] : 0;
        __syncthreads();
        s[t] += a;
        __syncthreads();
    }
    partials[t] = s[t] - v;                          // exclusive
}

// ---------------- scan stage 3: row_start + cursors + dis ------------------
__global__ __launch_bounds__(256) void k_scan_final(const int* __restrict__ cnt,
                                                    const int* __restrict__ partials,
                                                    int* row_start, int* cur,
                                                    float* dis) {
    __shared__ int s[256];
    int t = threadIdx.x;
    int i = blockIdx.x * 256 + t;
    int v = cnt[i];
    s[t] = v;
    __syncthreads();
    for (int off = 1; off < 256; off <<= 1) {
        int a = (t >= off) ? s[t - off] : 0;
        __syncthreads();
        s[t] += a;
        __syncthreads();
    }
    int base = partials[blockIdx.x];
    int excl = base + s[t] - v;
    if (i < N_NODES) {
        row_start[i] = excl;
        cur[i] = excl;
        dis[i] = rsqrtf((float)(v + 1));             // self-loop included
    }
    if (i == N_NODES - 1) row_start[N_NODES] = excl + v;   // == N_EDGES
}

// ---------------- scatter edges (packed src+norm, one 8B store) ------------
__global__ __launch_bounds__(256) void k_scatter(const int* __restrict__ ei,
                                                 const float* __restrict__ dis,
                                                 int* cur, int2* __restrict__ pk) {
    int e = blockIdx.x * 256 + threadIdx.x;
    if (e >= N_EDGES) return;
    int s = ei[e], d = ei[N_EDGES + e];
    int pos = atomicAdd(&cur[d], 1);
    pk[pos] = make_int2(s, __float_as_int(dis[s] * dis[d]));
}

// ---------------- t1 = x @ W1, register-tiled 4x4 --------------------------
// block = 64 nodes x 64 ch; thread tile = 4 nodes x 4 ch (float4 accs).
// x staged transposed into LDS with XOR swizzle -> both reads are ds_read_b128,
// conflict-free (2-way max). K processed in 2 halves of 64 (32 KB LDS total).
__global__ __launch_bounds__(256) void k_mm1(const float* __restrict__ x,
                                             const float* __restrict__ W1,
                                             float* __restrict__ t1) {
    __shared__ float4 ws[64 * 16];      // W half-tile [k][cq], 16 KB
    __shared__ float  xsT[64 * 64];     // x half-tile, transposed+swizzled, 16 KB
    int t = threadIdx.x;
    int n0 = blockIdx.x * 64;
    int lane = t & 63, wv_ = t >> 6;
    int ni = lane >> 2;                 // node-quad 0..15 (nodes 4ni..4ni+3)
    int cq = ((lane & 3) << 2) + wv_;   // channel-quad 0..15 (ch 4cq..4cq+3)
    const float4* W4 = (const float4*)W1;
    const float4* x4 = (const float4*)x;
    float4 acc0 = {0,0,0,0}, acc1 = acc0, acc2 = acc0, acc3 = acc0;
#pragma unroll
    for (int kt = 0; kt < 2; ++kt) {
        __syncthreads();
#pragma unroll
        for (int i = 0; i < 4; ++i) {
            int L = i * 256 + t;
            ws[L] = W4[kt * 1024 + L];              // W[k][cq], k = L>>4 in half
            int n = L >> 4, q = L & 15;             // node, k-quad within half
            int ng = n0 + n; if (ng >= N_NODES) ng = N_NODES - 1;
            float4 v = x4[ng * 32 + kt * 16 + q];   // x[ng][4q..4q+3] of half
            int fb = q * 256 + (((n >> 2) ^ q) << 2) + (n & 3);  // swizzled
            xsT[fb]       = v.x;                    // k_l=4q+0, 2-way banks
            xsT[fb + 64]  = v.y;
            xsT[fb + 128] = v.z;
            xsT[fb + 192] = v.w;
        }
        __syncthreads();
        const float4* xsT4 = (const float4*)xsT;
#pragma unroll 8
        for (int k = 0; k < 64; ++k) {
            float4 xv = xsT4[k * 16 + (ni ^ (k >> 2))];   // nodes 4ni..4ni+3 at k
            float4 wvv = ws[k * 16 + cq];                 // ch 4cq..4cq+3 at k
            acc0.x += xv.x * wvv.x; acc0.y += xv.x * wvv.y; acc0.z += xv.x * wvv.z; acc0.w += xv.x * wvv.w;
            acc1.x += xv.y * wvv.x; acc1.y += xv.y * wvv.y; acc1.z += xv.y * wvv.z; acc1.w += xv.y * wvv.w;
            acc2.x += xv.z * wvv.x; acc2.y += xv.z * wvv.y; acc2.z += xv.z * wvv.z; acc2.w += xv.z * wvv.w;
            acc3.x += xv.w * wvv.x; acc3.y += xv.w * wvv.y; acc3.z += xv.w * wvv.z; acc3.w += xv.w * wvv.w;
        }
    }
    int nb = n0 + 4 * ni;               // N%4==0: all-or-nothing validity
    if (nb < N_NODES) {
        float4* o4 = (float4*)t1;
        o4[(nb + 0) * 16 + cq] = acc0;
        o4[(nb + 1) * 16 + cq] = acc1;
        o4[(nb + 2) * 16 + cq] = acc2;
        o4[(nb + 3) * 16 + cq] = acc3;
    }
}

// ---------------- pull aggregation, 4 edges/instr, unroll 4 ----------------
__global__ __launch_bounds__(256) void k_agg4(const int2* __restrict__ pk,
                                              const int* __restrict__ row_start,
                                              const float* __restrict__ dis,
                                              const float* __restrict__ in,
                                              const float* __restrict__ bias,
                                              float* __restrict__ out,
                                              int apply_relu) {
    int w = (blockIdx.x * 256 + threadIdx.x) >> 6;
    if (w >= N_NODES) return;
    int lane = threadIdx.x & 63;
    int egrp = lane >> 4, csub = lane & 15;
    int beg = row_start[w], end = row_start[w + 1];
    const float4* __restrict__ in4 = (const float4*)in;
    float4 acc = make_float4(0.f, 0.f, 0.f, 0.f);
#pragma unroll 4
    for (int base = beg; base < end; base += 4) {
        int je = base + egrp;                        // pk padded by 16 entries
        int2 p = pk[je];
        float nv = (je < end) ? __int_as_float(p.y) : 0.0f;
        float4 v = in4[p.x * 16 + csub];
        acc.x += nv * v.x; acc.y += nv * v.y;
        acc.z += nv * v.z; acc.w += nv * v.w;
    }
    for (int m = 16; m <= 32; m <<= 1) {
        acc.x += __shfl_xor(acc.x, m, 64);
        acc.y += __shfl_xor(acc.y, m, 64);
        acc.z += __shfl_xor(acc.z, m, 64);
        acc.w += __shfl_xor(acc.w, m, 64);
    }
    if (egrp == 0) {
        float r = dis[w]; float rr = r * r;
        float4 sv = in4[w * 16 + csub];              // self-loop
        acc.x += rr * sv.x; acc.y += rr * sv.y;
        acc.z += rr * sv.z; acc.w += rr * sv.w;
        if (apply_relu) {
            float4 b = ((const float4*)bias)[csub];
            acc.x = fmaxf(acc.x + b.x, 0.f);
            acc.y = fmaxf(acc.y + b.y, 0.f);
            acc.z = fmaxf(acc.z + b.z, 0.f);
            acc.w = fmaxf(acc.w + b.w, 0.f);
        }
        ((float4*)out)[w * 16 + csub] = acc;
    }
}

// ---------------- out = agg2 @ [W_mu | W_logstd] + bias, 4x4 tiled ---------
// Same skeleton as k_mm1, K=64 single tile. cq<8 -> mu channels, cq>=8 -> ls.
__global__ __launch_bounds__(256) void k_mm2(const float* __restrict__ agg2,
                                             const float* __restrict__ Wmu,
                                             const float* __restrict__ bmu,
                                             const float* __restrict__ Wls,
                                             const float* __restrict__ bls,
                                             float* __restrict__ out) {
    __shared__ float4 ws[64 * 16];      // [Wmu|Wls] combined [k][cq], 16 KB
    __shared__ float  xsT[64 * 64];     // agg2 tile transposed+swizzled, 16 KB
    int t = threadIdx.x;
    int n0 = blockIdx.x * 64;
    int lane = t & 63, wv_ = t >> 6;
    int ni = lane >> 2;
    int cq = ((lane & 3) << 2) + wv_;
    const float4* Wm4 = (const float4*)Wmu;
    const float4* Wl4 = (const float4*)Wls;
    const float4* x4  = (const float4*)agg2;
#pragma unroll
    for (int i = 0; i < 4; ++i) {
        int L = i * 256 + t;
        int k = L >> 4, c = L & 15;
        ws[L] = (c < 8) ? Wm4[k * 8 + c] : Wl4[k * 8 + (c - 8)];
        int n = L >> 4, q = L & 15;
        int ng = n0 + n; if (ng >= N_NODES) ng = N_NODES - 1;
        float4 v = x4[ng * 16 + q];
        int fb = q * 256 + (((n >> 2) ^ q) << 2) + (n & 3);
        xsT[fb]       = v.x;
        xsT[fb + 64]  = v.y;
        xsT[fb + 128] = v.z;
        xsT[fb + 192] = v.w;
    }
    float4 b = (cq < 8) ? ((const float4*)bmu)[cq] : ((const float4*)bls)[cq - 8];
    float4 acc0 = b, acc1 = b, acc2 = b, acc3 = b;
    __syncthreads();
    const float4* xsT4 = (const float4*)xsT;
#pragma unroll 8
    for (int k = 0; k < 64; ++k) {
        float4 xv = xsT4[k * 16 + (ni ^ (k >> 2))];
        float4 wvv = ws[k * 16 + cq];
        acc0.x += xv.x * wvv.x; acc0.y += xv.x * wvv.y; acc0.z += xv.x * wvv.z; acc0.w += xv.x * wvv.w;
        acc1.x += xv.y * wvv.x; acc1.y += xv.y * wvv.y; acc1.z += xv.y * wvv.z; acc1.w += xv.y * wvv.w;
        acc2.x += xv.z * wvv.x; acc2.y += xv.z * wvv.y; acc2.z += xv.z * wvv.z; acc2.w += xv.z * wvv.w;
        acc3.x += xv.w * wvv.x; acc3.y += xv.w * wvv.y; acc3.z += xv.w * wvv.z; acc3.w += xv.w * wvv.w;
    }
    int nb = n0 + 4 * ni;
    if (nb < N_NODES) {
        float4* o4 = (float4*)out;
        // mu rows at [0, N*32), logstd rows at [N*32, N*64) — both 8 float4/row
        long base_off = (cq < 8) ? 0 : (long)N_NODES * 8;
        int cq8 = cq & 7;
        o4[base_off + (long)(nb + 0) * 8 + cq8] = acc0;
        o4[base_off + (long)(nb + 1) * 8 + cq8] = acc1;
        o4[base_off + (long)(nb + 2) * 8 + cq8] = acc2;
        o4[base_off + (long)(nb + 3) * 8 + cq8] = acc3;
    }
}

extern "C" void kernel_launch(void* const* d_in, const int* in_sizes, int n_in,
                              void* d_out, int out_size, void* d_ws, size_t ws_size,
                              hipStream_t stream) {
    const float* x   = (const float*)d_in[0];
    const int*   ei  = (const int*)  d_in[1];
    const float* W1  = (const float*)d_in[2];
    const float* b1  = (const float*)d_in[3];
    const float* Wmu = (const float*)d_in[4];
    const float* bmu = (const float*)d_in[5];
    const float* Wls = (const float*)d_in[6];
    const float* bls = (const float*)d_in[7];
    float* out = (float*)d_out;

    // workspace layout (4-byte units)
    int*   cnt       = (int*)d_ws;                       // [0, 50176)
    float* dis       = (float*)d_ws + 50176;             // 50000
    int*   row_start = (int*)d_ws + 100176;              // 50001 -> pad 150208
    int*   cur       = (int*)d_ws + 150208;              // 50000
    int*   partials  = (int*)d_ws + 200208;              // 256 -> pad 200512
    int2*  pk        = (int2*)((int*)d_ws + 200512);     // 800016 pairs
    float* bufA      = (float*)d_ws + 1800576;           // 3.2M (t1, then agg2)
    float* bufB      = (float*)d_ws + 5000576;           // 3.2M (h)

    k_zero_i       <<<NBLK, 256, 0, stream>>>(cnt, pk);
    k_hist         <<<3125, 256, 0, stream>>>(ei, cnt);
    k_block_sum    <<<NBLK, 256, 0, stream>>>(cnt, partials);
    k_scan_partials<<<1,    256, 0, stream>>>(partials);
    k_scan_final   <<<NBLK, 256, 0, stream>>>(cnt, partials, row_start, cur, dis);
    k_scatter      <<<3125, 256, 0, stream>>>(ei, dis, cur, pk);
    k_mm1          <<<782,  256, 0, stream>>>(x, W1, bufA);
    k_agg4         <<<12500, 256, 0, stream>>>(pk, row_start, dis, bufA, b1, bufB, 1);
    k_agg4         <<<12500, 256, 0, stream>>>(pk, row_start, dis, bufB, nullptr, bufA, 0);
    k_mm2          <<<782,  256, 0, stream>>>(bufA, Wmu, bmu, Wls, bls, out);
}

// Round 5
// 237.964 us; speedup vs baseline: 2.6317x; 1.0961x over previous
//
#include <hip/hip_runtime.h>
#include <hip/hip_fp16.h>

#define N_NODES 50000
#define N_EDGES 800000
#define IN_CH 128
#define HID 64
#define OUT_CH 32
#define NBLK 196                 // ceil(50000/256) blocks for node-sized kernels
#define NPART 8                  // dst partitions ~ XCDs (blockIdx & 7 swizzle)
#define PART_SZ 6250             // N_NODES / NPART

union H4 { uint2 u; __half2 h[2]; };

// ---------------- zero counters + pk tail pad ------------------------------
__global__ __launch_bounds__(256) void k_zero_i(int* cnt, int2* pk) {
    int i = blockIdx.x * 256 + threadIdx.x;
    cnt[i] = 0;                                      // covers 50176 (padded)
    if (i < 16) pk[N_EDGES + i] = make_int2(0, 0);   // pad for 8-wide agg reads
}

// ---------------- histogram of dst, XCD-partitioned ------------------------
// part = blockIdx&7 -> same XCD (heuristic): cnt slice stays in one L2.
__global__ __launch_bounds__(256) void k_hist(const int* __restrict__ ei, int* cnt) {
    int part = blockIdx.x & 7;
    int e = (blockIdx.x >> 3) * 256 + threadIdx.x;
    if (e >= N_EDGES) return;
    int d = ei[N_EDGES + e];
    if (d / PART_SZ != part) return;
    atomicAdd(&cnt[d], 1);
}

// ---------------- scan stage 1: per-block sums -----------------------------
__global__ __launch_bounds__(256) void k_block_sum(const int* __restrict__ cnt, int* partials) {
    __shared__ int s[256];
    int t = threadIdx.x;
    s[t] = cnt[blockIdx.x * 256 + t];
    __syncthreads();
    for (int off = 128; off > 0; off >>= 1) {
        if (t < off) s[t] += s[t + off];
        __syncthreads();
    }
    if (t == 0) partials[blockIdx.x] = s[0];
}

// ---------------- scan stage 2: exclusive scan of partials (1 block) -------
__global__ __launch_bounds__(256) void k_scan_partials(int* partials) {
    __shared__ int s[256];
    int t = threadIdx.x;
    int v = (t < NBLK) ? partials[t] : 0;
    s[t] = v;
    __syncthreads();
    for (int off = 1; off < 256; off <<= 1) {
        int a = (t >= off) ? s[t - off] : 0;
        __syncthreads();
        s[t] += a;
        __syncthreads();
    }
    partials[t] = s[t] - v;                          // exclusive
}

// ---------------- scan stage 3: row_start + cursors + dis ------------------
__global__ __launch_bounds__(256) void k_scan_final(const int* __restrict__ cnt,
                                                    const int* __restrict__ partials,
                                                    int* row_start, int* cur,
                                                    float* dis) {
    __shared__ int s[256];
    int t = threadIdx.x;
    int i = blockIdx.x * 256 + t;
    int v = cnt[i];
    s[t] = v;
    __syncthreads();
    for (int off = 1; off < 256; off <<= 1) {
        int a = (t >= off) ? s[t - off] : 0;
        __syncthreads();
        s[t] += a;
        __syncthreads();
    }
    int base = partials[blockIdx.x];
    int excl = base + s[t] - v;
    if (i < N_NODES) {
        row_start[i] = excl;
        cur[i] = excl;
        dis[i] = rsqrtf((float)(v + 1));             // self-loop included
    }
    if (i == N_NODES - 1) row_start[N_NODES] = excl + v;   // == N_EDGES
}

// ---------------- scatter edges, XCD-partitioned ---------------------------
// Partition p writes only its contiguous pk slice + its cur slice -> stores
// to a given line originate from one XCD, close in time -> lines coalesce.
__global__ __launch_bounds__(256) void k_scatter(const int* __restrict__ ei,
                                                 const float* __restrict__ dis,
                                                 int* cur, int2* __restrict__ pk) {
    int part = blockIdx.x & 7;
    int e = (blockIdx.x >> 3) * 256 + threadIdx.x;
    if (e >= N_EDGES) return;
    int d = ei[N_EDGES + e];
    if (d / PART_SZ != part) return;
    int s = ei[e];
    int pos = atomicAdd(&cur[d], 1);
    pk[pos] = make_int2(s, __float_as_int(dis[s] * dis[d]));
}

// ---------------- t1 = x @ W1, register-tiled 4x4, half output -------------
__global__ __launch_bounds__(256) void k_mm1(const float* __restrict__ x,
                                             const float* __restrict__ W1,
                                             __half* __restrict__ t1) {
    __shared__ float4 ws[64 * 16];      // W half-tile [k][cq], 16 KB
    __shared__ float  xsT[64 * 64];     // x half-tile, transposed+swizzled, 16 KB
    int t = threadIdx.x;
    int n0 = blockIdx.x * 64;
    int lane = t & 63, wv_ = t >> 6;
    int ni = lane >> 2;                 // node-quad 0..15
    int cq = ((lane & 3) << 2) + wv_;   // channel-quad 0..15
    const float4* W4 = (const float4*)W1;
    const float4* x4 = (const float4*)x;
    float4 acc0 = {0,0,0,0}, acc1 = acc0, acc2 = acc0, acc3 = acc0;
#pragma unroll
    for (int kt = 0; kt < 2; ++kt) {
        __syncthreads();
#pragma unroll
        for (int i = 0; i < 4; ++i) {
            int L = i * 256 + t;
            ws[L] = W4[kt * 1024 + L];
            int n = L >> 4, q = L & 15;
            int ng = n0 + n; if (ng >= N_NODES) ng = N_NODES - 1;
            float4 v = x4[ng * 32 + kt * 16 + q];
            int fb = q * 256 + (((n >> 2) ^ q) << 2) + (n & 3);
            xsT[fb]       = v.x;
            xsT[fb + 64]  = v.y;
            xsT[fb + 128] = v.z;
            xsT[fb + 192] = v.w;
        }
        __syncthreads();
        const float4* xsT4 = (const float4*)xsT;
#pragma unroll 8
        for (int k = 0; k < 64; ++k) {
            float4 xv = xsT4[k * 16 + (ni ^ (k >> 2))];
            float4 wvv = ws[k * 16 + cq];
            acc0.x += xv.x * wvv.x; acc0.y += xv.x * wvv.y; acc0.z += xv.x * wvv.z; acc0.w += xv.x * wvv.w;
            acc1.x += xv.y * wvv.x; acc1.y += xv.y * wvv.y; acc1.z += xv.y * wvv.z; acc1.w += xv.y * wvv.w;
            acc2.x += xv.z * wvv.x; acc2.y += xv.z * wvv.y; acc2.z += xv.z * wvv.z; acc2.w += xv.z * wvv.w;
            acc3.x += xv.w * wvv.x; acc3.y += xv.w * wvv.y; acc3.z += xv.w * wvv.z; acc3.w += xv.w * wvv.w;
        }
    }
    int nb = n0 + 4 * ni;
    if (nb < N_NODES) {
        uint2* o2 = (uint2*)t1;                      // 16 uint2 per 64-half row
        H4 v;
        v.h[0] = __floats2half2_rn(acc0.x, acc0.y); v.h[1] = __floats2half2_rn(acc0.z, acc0.w);
        o2[(nb + 0) * 16 + cq] = v.u;
        v.h[0] = __floats2half2_rn(acc1.x, acc1.y); v.h[1] = __floats2half2_rn(acc1.z, acc1.w);
        o2[(nb + 1) * 16 + cq] = v.u;
        v.h[0] = __floats2half2_rn(acc2.x, acc2.y); v.h[1] = __floats2half2_rn(acc2.z, acc2.w);
        o2[(nb + 2) * 16 + cq] = v.u;
        v.h[0] = __floats2half2_rn(acc3.x, acc3.y); v.h[1] = __floats2half2_rn(acc3.z, acc3.w);
        o2[(nb + 3) * 16 + cq] = v.u;
    }
}

// ---------------- pull aggregation, half payload, 8 edges/instr ------------
// wave = 8 edge-groups x 8 lanes; lane loads uint4 = 8 halves (16B) -> one
// gather instruction covers 8 independent edges.
__global__ __launch_bounds__(256) void k_agg8(const int2* __restrict__ pk,
                                              const int* __restrict__ row_start,
                                              const float* __restrict__ dis,
                                              const __half* __restrict__ in,
                                              const float* __restrict__ bias,
                                              __half* __restrict__ out,
                                              int apply_relu) {
    int w = (blockIdx.x * 256 + threadIdx.x) >> 6;
    if (w >= N_NODES) return;
    int lane = threadIdx.x & 63;
    int eg = lane >> 3, cs = lane & 7;
    int beg = row_start[w], end = row_start[w + 1];
    const uint4* __restrict__ inv = (const uint4*)in;    // 8 uint4 per row
    float acc[8] = {0,0,0,0,0,0,0,0};
#pragma unroll 2
    for (int base = beg; base < end; base += 8) {
        int je = base + eg;                          // pk padded by 16 entries
        int2 p = pk[je];
        float nv = (je < end) ? __int_as_float(p.y) : 0.0f;
        uint4 r = inv[p.x * 8 + cs];
        const __half2* h2 = (const __half2*)&r;
        float2 f;
        f = __half22float2(h2[0]); acc[0] += nv * f.x; acc[1] += nv * f.y;
        f = __half22float2(h2[1]); acc[2] += nv * f.x; acc[3] += nv * f.y;
        f = __half22float2(h2[2]); acc[4] += nv * f.x; acc[5] += nv * f.y;
        f = __half22float2(h2[3]); acc[6] += nv * f.x; acc[7] += nv * f.y;
    }
#pragma unroll
    for (int m = 8; m <= 32; m <<= 1)
#pragma unroll
        for (int i = 0; i < 8; ++i) acc[i] += __shfl_xor(acc[i], m, 64);
    if (eg == 0) {
        float r0 = dis[w], rr = r0 * r0;
        uint4 sr = inv[w * 8 + cs];                  // self-loop
        const __half2* sh = (const __half2*)&sr;
        float2 f;
        f = __half22float2(sh[0]); acc[0] += rr * f.x; acc[1] += rr * f.y;
        f = __half22float2(sh[1]); acc[2] += rr * f.x; acc[3] += rr * f.y;
        f = __half22float2(sh[2]); acc[4] += rr * f.x; acc[5] += rr * f.y;
        f = __half22float2(sh[3]); acc[6] += rr * f.x; acc[7] += rr * f.y;
        if (apply_relu) {
            float4 b0 = ((const float4*)bias)[2 * cs];
            float4 b1 = ((const float4*)bias)[2 * cs + 1];
            acc[0] = fmaxf(acc[0] + b0.x, 0.f); acc[1] = fmaxf(acc[1] + b0.y, 0.f);
            acc[2] = fmaxf(acc[2] + b0.z, 0.f); acc[3] = fmaxf(acc[3] + b0.w, 0.f);
            acc[4] = fmaxf(acc[4] + b1.x, 0.f); acc[5] = fmaxf(acc[5] + b1.y, 0.f);
            acc[6] = fmaxf(acc[6] + b1.z, 0.f); acc[7] = fmaxf(acc[7] + b1.w, 0.f);
        }
        __half2 o[4];
        o[0] = __floats2half2_rn(acc[0], acc[1]);
        o[1] = __floats2half2_rn(acc[2], acc[3]);
        o[2] = __floats2half2_rn(acc[4], acc[5]);
        o[3] = __floats2half2_rn(acc[6], acc[7]);
        ((uint4*)out)[w * 8 + cs] = *(const uint4*)o;
    }
}

// ---------------- out = agg2 @ [W_mu | W_logstd] + bias, 4x4 tiled ---------
__global__ __launch_bounds__(256) void k_mm2(const __half* __restrict__ agg2,
                                             const float* __restrict__ Wmu,
                                             const float* __restrict__ bmu,
                                             const float* __restrict__ Wls,
                                             const float* __restrict__ bls,
                                             float* __restrict__ out) {
    __shared__ float4 ws[64 * 16];      // [Wmu|Wls] combined [k][cq], 16 KB
    __shared__ float  xsT[64 * 64];     // agg2 tile transposed+swizzled, 16 KB
    int t = threadIdx.x;
    int n0 = blockIdx.x * 64;
    int lane = t & 63, wv_ = t >> 6;
    int ni = lane >> 2;
    int cq = ((lane & 3) << 2) + wv_;
    const float4* Wm4 = (const float4*)Wmu;
    const float4* Wl4 = (const float4*)Wls;
    const uint2*  x2  = (const uint2*)agg2;          // 16 uint2 per 64-half row
#pragma unroll
    for (int i = 0; i < 4; ++i) {
        int L = i * 256 + t;
        int k = L >> 4, c = L & 15;
        ws[L] = (c < 8) ? Wm4[k * 8 + c] : Wl4[k * 8 + (c - 8)];
        int n = L >> 4, q = L & 15;
        int ng = n0 + n; if (ng >= N_NODES) ng = N_NODES - 1;
        H4 hv; hv.u = x2[ng * 16 + q];
        float2 f0 = __half22float2(hv.h[0]), f1 = __half22float2(hv.h[1]);
        int fb = q * 256 + (((n >> 2) ^ q) << 2) + (n & 3);
        xsT[fb]       = f0.x;
        xsT[fb + 64]  = f0.y;
        xsT[fb + 128] = f1.x;
        xsT[fb + 192] = f1.y;
    }
    float4 b = (cq < 8) ? ((const float4*)bmu)[cq] : ((const float4*)bls)[cq - 8];
    float4 acc0 = b, acc1 = b, acc2 = b, acc3 = b;
    __syncthreads();
    const float4* xsT4 = (const float4*)xsT;
#pragma unroll 8
    for (int k = 0; k < 64; ++k) {
        float4 xv = xsT4[k * 16 + (ni ^ (k >> 2))];
        float4 wvv = ws[k * 16 + cq];
        acc0.x += xv.x * wvv.x; acc0.y += xv.x * wvv.y; acc0.z += xv.x * wvv.z; acc0.w += xv.x * wvv.w;
        acc1.x += xv.y * wvv.x; acc1.y += xv.y * wvv.y; acc1.z += xv.y * wvv.z; acc1.w += xv.y * wvv.w;
        acc2.x += xv.z * wvv.x; acc2.y += xv.z * wvv.y; acc2.z += xv.z * wvv.z; acc2.w += xv.z * wvv.w;
        acc3.x += xv.w * wvv.x; acc3.y += xv.w * wvv.y; acc3.z += xv.w * wvv.z; acc3.w += xv.w * wvv.w;
    }
    int nb = n0 + 4 * ni;
    if (nb < N_NODES) {
        float4* o4 = (float4*)out;
        long base_off = (cq < 8) ? 0 : (long)N_NODES * 8;
        int cq8 = cq & 7;
        o4[base_off + (long)(nb + 0) * 8 + cq8] = acc0;
        o4[base_off + (long)(nb + 1) * 8 + cq8] = acc1;
        o4[base_off + (long)(nb + 2) * 8 + cq8] = acc2;
        o4[base_off + (long)(nb + 3) * 8 + cq8] = acc3;
    }
}

extern "C" void kernel_launch(void* const* d_in, const int* in_sizes, int n_in,
                              void* d_out, int out_size, void* d_ws, size_t ws_size,
                              hipStream_t stream) {
    const float* x   = (const float*)d_in[0];
    const int*   ei  = (const int*)  d_in[1];
    const float* W1  = (const float*)d_in[2];
    const float* b1  = (const float*)d_in[3];
    const float* Wmu = (const float*)d_in[4];
    const float* bmu = (const float*)d_in[5];
    const float* Wls = (const float*)d_in[6];
    const float* bls = (const float*)d_in[7];
    float* out = (float*)d_out;

    // workspace layout (4-byte units)
    int*   cnt       = (int*)d_ws;                       // [0, 50176)
    float* dis       = (float*)d_ws + 50176;             // 50000
    int*   row_start = (int*)d_ws + 100176;              // 50001 -> pad 150208
    int*   cur       = (int*)d_ws + 150208;              // 50000
    int*   partials  = (int*)d_ws + 200208;              // 256 -> pad 200512
    int2*  pk        = (int2*)((int*)d_ws + 200512);     // 800016 pairs
    __half* bufA     = (__half*)((int*)d_ws + 1800576);  // t1, then agg2 (half)
    __half* bufB     = (__half*)((int*)d_ws + 5000576);  // h (half)

    k_zero_i       <<<NBLK, 256, 0, stream>>>(cnt, pk);
    k_hist         <<<3125 * NPART, 256, 0, stream>>>(ei, cnt);
    k_block_sum    <<<NBLK, 256, 0, stream>>>(cnt, partials);
    k_scan_partials<<<1,    256, 0, stream>>>(partials);
    k_scan_final   <<<NBLK, 256, 0, stream>>>(cnt, partials, row_start, cur, dis);
    k_scatter      <<<3125 * NPART, 256, 0, stream>>>(ei, dis, cur, pk);
    k_mm1          <<<782,  256, 0, stream>>>(x, W1, bufA);
    k_agg8         <<<12500, 256, 0, stream>>>(pk, row_start, dis, bufA, b1, bufB, 1);
    k_agg8         <<<12500, 256, 0, stream>>>(pk, row_start, dis, bufB, nullptr, bufA, 0);
    k_mm2          <<<782,  256, 0, stream>>>(bufA, Wmu, bmu, Wls, bls, out);
}